// Round 9
// baseline (186.008 us; speedup 1.0000x reference)
//
#include <hip/hip_runtime.h>
#include <cstddef>

#define B_ 16
#define CIN_ 256
#define H_ 32
#define W_ 32
#define HW_ 1024
#define COUT_ 256
#define DK_ 128
#define DV_ 128
#define NH_ 8
#define DKH_ 16
#define DVH_ 16
#define CCONV_ 128
#define QKVO_ 384

typedef __attribute__((ext_vector_type(4))) _Float16 half4v;
typedef __attribute__((ext_vector_type(8))) _Float16 half8v;
typedef __attribute__((ext_vector_type(4))) float float4v;

// log2(e) folded into Q so attention uses raw v_exp_f32 (2^x): 2^(s*log2e) == e^s.
#define QSCALE 0.36067376022224085f   // 0.25 * log2(e)

// ---------------- K0: x -> xF[b][kc(8)][pix(1024)][k32(32)] (f16) ----------------
__global__ __launch_bounds__(256) void xt_kernel(
    const float* __restrict__ x, _Float16* __restrict__ xF)
{
    const int pt = blockIdx.x;   // 0..31 pixel tile
    const int ct = blockIdx.y;   // 0..7  ci tile (32 ch)
    const int b  = blockIdx.z;
    __shared__ float T[32][33];
    const int t = threadIdx.x;
    const int c = t & 31, r = t >> 5;
#pragma unroll
    for (int i = 0; i < 4; ++i) {
        const int ci = ct * 32 + r + i * 8;
        T[r + i * 8][c] = x[(size_t)(b * CIN_ + ci) * HW_ + pt * 32 + c];
    }
    __syncthreads();
    const int cq = (t & 7) * 4;      // ci quad within the 32-chunk
    const int pi = t >> 3;           // pixel within tile
    half4v h;
#pragma unroll
    for (int j = 0; j < 4; ++j) h[j] = (_Float16)T[cq + j][pi];
    const int p = pt * 32 + pi;
    *(half4v*)(xF + ((size_t)(b * 8 + ct) * HW_ + p) * 32 + cq) = h;
}

// ---------------- K0b: weight prep (merged, K32 fragment-major) ----------------
__global__ __launch_bounds__(256) void wprep_kernel(
    const float* __restrict__ conv_w, const float* __restrict__ qkv_w,
    const float* __restrict__ attn_w, _Float16* __restrict__ wC,
    _Float16* __restrict__ wF, _Float16* __restrict__ wP)
{
    const int bid = blockIdx.x;
    const int t = threadIdx.x;
    if (bid < 128) {
        const int id = bid * 256 + t;             // co*256+ci
        const int co = id >> 8, ci = id & 255;
        const float* src = conv_w + (size_t)id * 9;
#pragma unroll
        for (int j = 0; j < 9; ++j)
            wC[(((size_t)(ci >> 5) * 9 + j) * 8 + (co >> 4)) * 512 + (co & 15) * 32 + (ci & 31)]
                = (_Float16)src[j];
    } else if (bid < 224) {
        const int g = (bid - 128) * 256 + t;      // < 24576
        const int o = g >> 6, k0 = (g & 63) * 4;
        const float4 v = *(const float4*)(qkv_w + (size_t)o * CIN_ + k0);
        half4v h; h[0] = (_Float16)v.x; h[1] = (_Float16)v.y;
        h[2] = (_Float16)v.z; h[3] = (_Float16)v.w;
        *(half4v*)(wF + ((size_t)(k0 >> 5) * QKVO_ + o) * 32 + (k0 & 31)) = h;
    } else {
        const int g = (bid - 224) * 256 + t;      // < 4096
        const int o = g >> 5, k0 = (g & 31) * 4;
        const float4 v = *(const float4*)(attn_w + (size_t)o * DV_ + k0);
        half4v h; h[0] = (_Float16)v.x; h[1] = (_Float16)v.y;
        h[2] = (_Float16)v.z; h[3] = (_Float16)v.w;
        *(half4v*)(wP + ((size_t)(k0 >> 5) * DV_ + o) * 32 + (k0 & 31)) = h;
    }
}

// ---------------- K1: qkv MFMA GEMM (K32, fragment-major, no LDS) ----------------
__global__ __launch_bounds__(256) void qkv_kernel(
    const _Float16* __restrict__ xF, const _Float16* __restrict__ wF,
    const float* __restrict__ qkv_b, _Float16* __restrict__ Qt,
    _Float16* __restrict__ Kt, _Float16* __restrict__ vF)
{
    const int pt = blockIdx.x;   // 0..15 (64 pixels)
    const int ot = blockIdx.y;   // 0..5  (64 outputs)
    const int b  = blockIdx.z;
    const int lane = threadIdx.x & 63, w = threadIdx.x >> 6;
    const int l16 = lane & 15, hi = lane >> 4;
    const int p0 = pt * 64;
    const int og = ot * 4 + w;           // 0..23: 0-7 Q, 8-15 K, 16-23 V
    const int o0 = og * 16;

    float4v acc[4];
#pragma unroll
    for (int pg = 0; pg < 4; ++pg) acc[pg] = (float4v){0.f, 0.f, 0.f, 0.f};

    for (int kc = 0; kc < 8; ++kc) {
        const half8v a = *(const half8v*)(wF + ((size_t)kc * QKVO_ + o0 + l16) * 32 + hi * 8);
#pragma unroll
        for (int pg = 0; pg < 4; ++pg) {
            const half8v bf = *(const half8v*)(xF + ((size_t)(b * 8 + kc) * HW_ + p0 + pg * 16 + l16) * 32 + hi * 8);
            acc[pg] = __builtin_amdgcn_mfma_f32_16x16x32_f16(a, bf, acc[pg], 0, 0, 0);
        }
    }

    float bias[4];
#pragma unroll
    for (int r = 0; r < 4; ++r) bias[r] = qkv_b[o0 + hi * 4 + r];

    if (og < 16) {
        const float scale = (og < 8) ? QSCALE : 1.0f;   // Q: DKH^-0.5 * log2e
        const int n = og & 7;
        _Float16* dst = (og < 8 ? Qt : Kt) + (size_t)(b * NH_ + n) * (HW_ * 16) + hi * 4;
#pragma unroll
        for (int pg = 0; pg < 4; ++pg) {
            const int p = p0 + pg * 16 + l16;
            half4v h;
#pragma unroll
            for (int r = 0; r < 4; ++r) h[r] = (_Float16)((acc[pg][r] + bias[r]) * scale);
            *(half4v*)(dst + (size_t)p * 16) = h;
        }
    } else {
        const int n = og - 16;
        _Float16* Vb = vF + (size_t)(b * NH_ + n) * (64 * 16 * 16);
#pragma unroll
        for (int pg = 0; pg < 4; ++pg) {
            const int qg = pt * 4 + pg;
#pragma unroll
            for (int r = 0; r < 4; ++r)
                Vb[(size_t)(qg * 16 + hi * 4 + r) * 16 + l16] = (_Float16)(acc[pg][r] + bias[r]);
        }
    }
}

// ---------------- K2: fused MFMA attention, q-split across wave pairs ----------------
// Wave (pg, qh): 64 pixels, half the q range; partials merged via LDS.
// S computed in log2-domain (Q pre-scaled by log2e) -> raw v_exp_f32.
__global__ __launch_bounds__(256) void attn_kernel(
    const _Float16* __restrict__ Qt, const _Float16* __restrict__ Kt,
    const _Float16* __restrict__ vF, _Float16* __restrict__ aF)
{
    const int bx = blockIdx.x;                 // ((b*8+n)*8 + pc)
    const int pc = bx & 7;
    const int n  = (bx >> 3) & 7;
    const int b  = bx >> 6;
    const int lane = threadIdx.x & 63, wave = threadIdx.x >> 6;
    const int pg = wave >> 1, qh = wave & 1;
    const int l16 = lane & 15, lg = lane >> 4;

    const int bn = b * NH_ + n;
    const _Float16* Qh = Qt + (size_t)bn * (HW_ * 16);
    const _Float16* Kh = Kt + (size_t)bn * (HW_ * 16);
    const _Float16* Vh = vF + (size_t)bn * (64 * 16 * 16);

    const int pbase = pc * 128 + pg * 64;

    half4v qf[4];
#pragma unroll
    for (int t = 0; t < 4; ++t)
        qf[t] = *(const half4v*)(Qh + (size_t)(pbase + t * 16 + l16) * 16 + lg * 4);

    float4v o[4];
    float rs[4];
#pragma unroll
    for (int t = 0; t < 4; ++t) { o[t] = (float4v){0.f, 0.f, 0.f, 0.f}; rs[t] = 0.f; }

    const float4v zero = (float4v){0.f, 0.f, 0.f, 0.f};

    const int q0beg = qh * 512;
    for (int q0 = q0beg; q0 < q0beg + 512; q0 += 16) {
        const half4v kf = *(const half4v*)(Kh + (size_t)(q0 + l16) * 16 + lg * 4);
        const half4v vf = *(const half4v*)(Vh + (size_t)((q0 >> 4) * 16 + l16) * 16 + lg * 4);
#pragma unroll
        for (int t = 0; t < 4; ++t) {
            float4v s = __builtin_amdgcn_mfma_f32_16x16x16f16(kf, qf[t], zero, 0, 0, 0);
            const float e0 = __builtin_amdgcn_exp2f(s[0]);
            const float e1 = __builtin_amdgcn_exp2f(s[1]);
            const float e2 = __builtin_amdgcn_exp2f(s[2]);
            const float e3 = __builtin_amdgcn_exp2f(s[3]);
            rs[t] += (e0 + e1) + (e2 + e3);
            half4v pf;
            pf[0] = (_Float16)e0; pf[1] = (_Float16)e1;
            pf[2] = (_Float16)e2; pf[3] = (_Float16)e3;
            o[t] = __builtin_amdgcn_mfma_f32_16x16x16f16(vf, pf, o[t], 0, 0, 0);
        }
    }

    __shared__ float Ored[2][64][16];
    __shared__ float Rred[2][64][4];
    if (qh == 1) {
#pragma unroll
        for (int t = 0; t < 4; ++t) {
#pragma unroll
            for (int rr = 0; rr < 4; ++rr) Ored[pg][lane][t * 4 + rr] = o[t][rr];
            Rred[pg][lane][t] = rs[t];
        }
    }
    __syncthreads();
    if (qh == 0) {
#pragma unroll
        for (int t = 0; t < 4; ++t) {
#pragma unroll
            for (int rr = 0; rr < 4; ++rr) o[t][rr] += Ored[pg][lane][t * 4 + rr];
            rs[t] += Rred[pg][lane][t];
        }
#pragma unroll
        for (int t = 0; t < 4; ++t) {
            float r = rs[t];
            r += __shfl_xor(r, 16);
            r += __shfl_xor(r, 32);
            const float inv = 1.0f / r;
            half4v h;
#pragma unroll
            for (int rr = 0; rr < 4; ++rr) h[rr] = (_Float16)(o[t][rr] * inv);
            // K32 layout: [b][pgrp][n>>1][p16][ (n&1)*16 + lg*4 ]
            *(half4v*)(aF + (((size_t)(b * 64 + (pbase >> 4) + t) * 4 + (n >> 1)) * 16 + l16) * 32
                          + (n & 1) * 16 + lg * 4) = h;
        }
    }
}

// ---------------- K3: attn projection MFMA GEMM (K32, no LDS) ----------------
__global__ __launch_bounds__(256) void proj_kernel(
    const _Float16* __restrict__ aF, const _Float16* __restrict__ wP,
    const float* __restrict__ attn_b, float* __restrict__ out)
{
    const int pt = blockIdx.x;   // 0..15 (64 pixels)
    const int ot = blockIdx.y;   // 0..1  (64 outputs)
    const int b  = blockIdx.z;
    const int lane = threadIdx.x & 63, w = threadIdx.x >> 6;
    const int l16 = lane & 15, hi = lane >> 4;
    const int p0 = pt * 64;
    const int o0 = ot * 64 + w * 16;

    float4v acc[4];
#pragma unroll
    for (int pg = 0; pg < 4; ++pg) acc[pg] = (float4v){0.f, 0.f, 0.f, 0.f};

    for (int kc = 0; kc < 4; ++kc) {
        const half8v a = *(const half8v*)(wP + ((size_t)kc * DV_ + o0 + l16) * 32 + hi * 8);
#pragma unroll
        for (int pg = 0; pg < 4; ++pg) {
            const half8v bf = *(const half8v*)(aF + (((size_t)(b * 64 + pt * 4 + pg) * 4 + kc) * 16 + l16) * 32 + hi * 8);
            acc[pg] = __builtin_amdgcn_mfma_f32_16x16x32_f16(a, bf, acc[pg], 0, 0, 0);
        }
    }
#pragma unroll
    for (int pg = 0; pg < 4; ++pg) {
        const int p = p0 + pg * 16 + l16;
#pragma unroll
        for (int r = 0; r < 4; ++r) {
            const int o = o0 + hi * 4 + r;
            out[((size_t)(b * COUT_ + CCONV_ + o)) * HW_ + p] = acc[pg][r] + attn_b[o];
        }
    }
}

// ---------------- K4: 3x3 conv, LDS-free implicit GEMM, K32 MFMA ----------------
// Wave: 1 row x 32 px x 16 co -> 4096 waves (4/SIMD). All waves of a block
// share the same row -> B loads broadcast via L1.
__global__ __launch_bounds__(256) void conv_kernel(
    const _Float16* __restrict__ xF, const _Float16* __restrict__ wC,
    const float* __restrict__ conv_b, float* __restrict__ out)
{
    const int r  = blockIdx.x;     // 0..31 output row
    const int ch = blockIdx.y;     // 0..1  co half
    const int b  = blockIdx.z;
    const int t = threadIdx.x;
    const int lane = t & 63, w = t >> 6;
    const int l16 = lane & 15, hi = lane >> 4;
    const int c16 = ch * 4 + w;          // 16-co chunk, 0..7

    const bool lane0bad  = (l16 == 0);   // col -1 at kw=0, frag0
    const bool lane15bad = (l16 == 15);  // col 32 at kw=2, frag1
    const half8v z = {0, 0, 0, 0, 0, 0, 0, 0};

    float4v acc[2];
    acc[0] = (float4v){0.f, 0.f, 0.f, 0.f};
    acc[1] = (float4v){0.f, 0.f, 0.f, 0.f};

    for (int kc = 0; kc < 8; ++kc) {
        const _Float16* xk = xF + ((size_t)(b * 8 + kc) * HW_ + r * 32) * 32 + l16 * 32 + hi * 8;
        const _Float16* ab = wC + ((size_t)(kc * 9) * 8 + c16) * 512 + l16 * 32 + hi * 8;
#pragma unroll
        for (int kh = 0; kh < 3; ++kh) {
            const int rr = r + kh - 1;
            if ((unsigned)rr >= 32u) continue;   // zero-pad row
#pragma unroll
            for (int kw = 0; kw < 3; ++kw) {
                const half8v a = *(const half8v*)(ab + (size_t)((kh * 3 + kw) * 8) * 512);
                const int sh = ((kh - 1) * 32 + (kw - 1)) * 32;   // halves
                half8v b0 = *(const half8v*)(xk + sh);
                half8v b1 = *(const half8v*)(xk + sh + 16 * 32);
                if (kw == 0) b0 = lane0bad  ? z : b0;
                if (kw == 2) b1 = lane15bad ? z : b1;
                acc[0] = __builtin_amdgcn_mfma_f32_16x16x32_f16(a, b0, acc[0], 0, 0, 0);
                acc[1] = __builtin_amdgcn_mfma_f32_16x16x32_f16(a, b1, acc[1], 0, 0, 0);
            }
        }
    }
#pragma unroll
    for (int rr = 0; rr < 4; ++rr) {
        const int co = c16 * 16 + hi * 4 + rr;
        const float bias = conv_b[co];
        float* dst = out + (size_t)(b * COUT_ + co) * HW_ + r * 32;
        dst[l16]      = acc[0][rr] + bias;
        dst[16 + l16] = acc[1][rr] + bias;
    }
}

extern "C" void kernel_launch(void* const* d_in, const int* in_sizes, int n_in,
                              void* d_out, int out_size, void* d_ws, size_t ws_size,
                              hipStream_t stream)
{
    (void)in_sizes; (void)n_in; (void)out_size; (void)ws_size;
    const float* x      = (const float*)d_in[0];
    const float* conv_w = (const float*)d_in[1];
    const float* conv_b = (const float*)d_in[2];
    const float* qkv_w  = (const float*)d_in[3];
    const float* qkv_b  = (const float*)d_in[4];
    const float* attn_w = (const float*)d_in[5];
    const float* attn_b = (const float*)d_in[6];
    float* out = (float*)d_out;

    char* ws = (char*)d_ws;
    // xF at +4096 so the conv halo's lane-0 read at base-64B stays inside d_ws.
    _Float16* xF = (_Float16*)(ws + 4096);          // 8,388,608
    _Float16* wC = (_Float16*)(ws + 8392704);       //   589,824
    _Float16* wF = (_Float16*)(ws + 8982528);       //   196,608
    _Float16* wP = (_Float16*)(ws + 9179136);       //    32,768
    _Float16* Qt = (_Float16*)(ws + 9211904);       // 4,194,304
    _Float16* Kt = (_Float16*)(ws + 13406208);      // 4,194,304
    _Float16* vF = (_Float16*)(ws + 17600512);      // 4,194,304
    _Float16* aF = (_Float16*)(ws + 21794816);      // 4,194,304 (end 25,989,120)

    xt_kernel<<<dim3(32, 8, B_), dim3(256), 0, stream>>>(x, xF);
    wprep_kernel<<<dim3(240), dim3(256), 0, stream>>>(conv_w, qkv_w, attn_w, wC, wF, wP);
    qkv_kernel<<<dim3(16, 6, B_), dim3(256), 0, stream>>>(xF, wF, qkv_b, Qt, Kt, vF);
    attn_kernel<<<dim3(1024), dim3(256), 0, stream>>>(Qt, Kt, vF, aF);
    proj_kernel<<<dim3(16, 2, B_), dim3(256), 0, stream>>>(aF, wP, attn_b, out);
    conv_kernel<<<dim3(32, 2, B_), dim3(256), 0, stream>>>(xF, wC, conv_b, out);
}

// Round 12
// 173.079 us; speedup vs baseline: 1.0747x; 1.0747x over previous
//
#include <hip/hip_runtime.h>
#include <cstddef>

#define B_ 16
#define CIN_ 256
#define H_ 32
#define W_ 32
#define HW_ 1024
#define COUT_ 256
#define DK_ 128
#define DV_ 128
#define NH_ 8
#define DKH_ 16
#define DVH_ 16
#define CCONV_ 128
#define QKVO_ 384

typedef __attribute__((ext_vector_type(4))) _Float16 half4v;
typedef __attribute__((ext_vector_type(8))) _Float16 half8v;
typedef __attribute__((ext_vector_type(4))) float float4v;

// log2(e) folded into Q so attention uses raw v_exp_f32 (2^x): 2^(s*log2e) == e^s.
#define QSCALE 0.36067376022224085f   // 0.25 * log2(e)

// xFs: three shifted+padded f16 copies of x, each [b][kc(8)][row 0..33][px 32][ci 32]:
//   copy0 = x[c]  (center), copy1 = x[c-1] (minus), copy2 = x[c+1] (plus);
//   rows 0 and 33 are zero; minus col0 = 0; plus col31 = 0.
// Conv tap (kh,kw) B-fragment = one contiguous 1KB wave load: no branches, no selects.
#define XFS_SZ ((size_t)16 * 8 * 34 * 1024)   // halves per copy

// ---------------- K0: x -> xFs[3] ----------------
__global__ __launch_bounds__(256) void xt_kernel(
    const float* __restrict__ x, _Float16* __restrict__ xFs)
{
    const int row = blockIdx.x;  // 0..31
    const int kc  = blockIdx.y;  // 0..7 (32-ci chunk)
    const int b   = blockIdx.z;
    __shared__ float T[32][33];
    const int t = threadIdx.x;
    const int c = t & 31, r = t >> 5;
#pragma unroll
    for (int i = 0; i < 4; ++i) {
        const int ci = kc * 32 + r + i * 8;
        T[r + i * 8][c] = x[(size_t)(b * CIN_ + ci) * HW_ + row * 32 + c];
    }
    __syncthreads();
    const int cq = (t & 7) * 4;
    const int pi = t >> 3;
    half4v h;
#pragma unroll
    for (int j = 0; j < 4; ++j) h[j] = (_Float16)T[cq + j][pi];
    const half4v z = {0, 0, 0, 0};
    const size_t bk = ((size_t)b * 8 + kc) * 34;
    const size_t rbase = (bk + row + 1) * 1024;
    // center
    *(half4v*)(xFs + rbase + pi * 32 + cq) = h;
    // minus copy: S1[c] = x[c-1] -> store at col pi+1; col 0 zeroed by pi==31 threads
    if (pi < 31) *(half4v*)(xFs + XFS_SZ + rbase + (pi + 1) * 32 + cq) = h;
    else         *(half4v*)(xFs + XFS_SZ + rbase + 0 * 32 + cq) = z;
    // plus copy: S2[c] = x[c+1] -> store at col pi-1; col 31 zeroed by pi==0 threads
    if (pi > 0)  *(half4v*)(xFs + 2 * XFS_SZ + rbase + (pi - 1) * 32 + cq) = h;
    else         *(half4v*)(xFs + 2 * XFS_SZ + rbase + 31 * 32 + cq) = z;
    // zero the pad rows (0 and 33) of all three copies
    if (row == 0) {
        for (int i = t; i < 1536; i += 256) {          // 3 copies x 2 rows x 256 quads
            const int s = i / 512;
            const int rm = (i / 256) & 1;
            const int q = (i & 255) * 4;
            *(half4v*)(xFs + (size_t)s * XFS_SZ + (bk + (rm ? 33 : 0)) * 1024 + q) = z;
        }
    }
}

// ---------------- K0b: weight prep (merged, K32 fragment-major) ----------------
__global__ __launch_bounds__(256) void wprep_kernel(
    const float* __restrict__ conv_w, const float* __restrict__ qkv_w,
    const float* __restrict__ attn_w, _Float16* __restrict__ wC,
    _Float16* __restrict__ wF, _Float16* __restrict__ wP)
{
    const int bid = blockIdx.x;
    const int t = threadIdx.x;
    if (bid < 128) {
        const int id = bid * 256 + t;             // co*256+ci
        const int co = id >> 8, ci = id & 255;
        const float* src = conv_w + (size_t)id * 9;
#pragma unroll
        for (int j = 0; j < 9; ++j)
            wC[(((size_t)(ci >> 5) * 9 + j) * 8 + (co >> 4)) * 512 + (co & 15) * 32 + (ci & 31)]
                = (_Float16)src[j];
    } else if (bid < 224) {
        const int g = (bid - 128) * 256 + t;      // < 24576
        const int o = g >> 6, k0 = (g & 63) * 4;
        const float4 v = *(const float4*)(qkv_w + (size_t)o * CIN_ + k0);
        half4v h; h[0] = (_Float16)v.x; h[1] = (_Float16)v.y;
        h[2] = (_Float16)v.z; h[3] = (_Float16)v.w;
        *(half4v*)(wF + ((size_t)(k0 >> 5) * QKVO_ + o) * 32 + (k0 & 31)) = h;
    } else {
        const int g = (bid - 224) * 256 + t;      // < 4096
        const int o = g >> 5, k0 = (g & 31) * 4;
        const float4 v = *(const float4*)(attn_w + (size_t)o * DV_ + k0);
        half4v h; h[0] = (_Float16)v.x; h[1] = (_Float16)v.y;
        h[2] = (_Float16)v.z; h[3] = (_Float16)v.w;
        *(half4v*)(wP + ((size_t)(k0 >> 5) * DV_ + o) * 32 + (k0 & 31)) = h;
    }
}

// ---------------- K1: qkv MFMA GEMM (K32, fragment-major, no LDS) ----------------
// B from the center xFs copy (row-padded: +1024 halves base offset).
__global__ __launch_bounds__(256) void qkv_kernel(
    const _Float16* __restrict__ xFs, const _Float16* __restrict__ wF,
    const float* __restrict__ qkv_b, _Float16* __restrict__ Qt,
    _Float16* __restrict__ Kt, _Float16* __restrict__ vF)
{
    const int pt = blockIdx.x;   // 0..15 (64 pixels)
    const int ot = blockIdx.y;   // 0..5  (64 outputs)
    const int b  = blockIdx.z;
    const int lane = threadIdx.x & 63, w = threadIdx.x >> 6;
    const int l16 = lane & 15, hi = lane >> 4;
    const int p0 = pt * 64;
    const int og = ot * 4 + w;           // 0..23: 0-7 Q, 8-15 K, 16-23 V
    const int o0 = og * 16;

    float4v acc[4];
#pragma unroll
    for (int pg = 0; pg < 4; ++pg) acc[pg] = (float4v){0.f, 0.f, 0.f, 0.f};

    for (int kc = 0; kc < 8; ++kc) {
        const half8v a = *(const half8v*)(wF + ((size_t)kc * QKVO_ + o0 + l16) * 32 + hi * 8);
        const _Float16* xb = xFs + (((size_t)b * 8 + kc) * 34 + 1) * 1024;
#pragma unroll
        for (int pg = 0; pg < 4; ++pg) {
            const half8v bf = *(const half8v*)(xb + (size_t)(p0 + pg * 16 + l16) * 32 + hi * 8);
            acc[pg] = __builtin_amdgcn_mfma_f32_16x16x32_f16(a, bf, acc[pg], 0, 0, 0);
        }
    }

    float bias[4];
#pragma unroll
    for (int r = 0; r < 4; ++r) bias[r] = qkv_b[o0 + hi * 4 + r];

    if (og < 16) {
        const float scale = (og < 8) ? QSCALE : 1.0f;   // Q: DKH^-0.5 * log2e
        const int n = og & 7;
        _Float16* dst = (og < 8 ? Qt : Kt) + (size_t)(b * NH_ + n) * (HW_ * 16) + hi * 4;
#pragma unroll
        for (int pg = 0; pg < 4; ++pg) {
            const int p = p0 + pg * 16 + l16;
            half4v h;
#pragma unroll
            for (int r = 0; r < 4; ++r) h[r] = (_Float16)((acc[pg][r] + bias[r]) * scale);
            *(half4v*)(dst + (size_t)p * 16) = h;
        }
    } else {
        const int n = og - 16;
        _Float16* Vb = vF + (size_t)(b * NH_ + n) * (64 * 16 * 16);
#pragma unroll
        for (int pg = 0; pg < 4; ++pg) {
            const int qg = pt * 4 + pg;
#pragma unroll
            for (int r = 0; r < 4; ++r)
                Vb[(size_t)(qg * 16 + hi * 4 + r) * 16 + l16] = (_Float16)(acc[pg][r] + bias[r]);
        }
    }
}

// ---------------- K2: fused MFMA attention, q-split across wave pairs (R9, verified) ----------------
__global__ __launch_bounds__(256) void attn_kernel(
    const _Float16* __restrict__ Qt, const _Float16* __restrict__ Kt,
    const _Float16* __restrict__ vF, _Float16* __restrict__ aF)
{
    const int bx = blockIdx.x;                 // ((b*8+n)*8 + pc)
    const int pc = bx & 7;
    const int n  = (bx >> 3) & 7;
    const int b  = bx >> 6;
    const int lane = threadIdx.x & 63, wave = threadIdx.x >> 6;
    const int pg = wave >> 1, qh = wave & 1;
    const int l16 = lane & 15, lg = lane >> 4;

    const int bn = b * NH_ + n;
    const _Float16* Qh = Qt + (size_t)bn * (HW_ * 16);
    const _Float16* Kh = Kt + (size_t)bn * (HW_ * 16);
    const _Float16* Vh = vF + (size_t)bn * (64 * 16 * 16);

    const int pbase = pc * 128 + pg * 64;

    half4v qf[4];
#pragma unroll
    for (int t = 0; t < 4; ++t)
        qf[t] = *(const half4v*)(Qh + (size_t)(pbase + t * 16 + l16) * 16 + lg * 4);

    float4v o[4];
    float rs[4];
#pragma unroll
    for (int t = 0; t < 4; ++t) { o[t] = (float4v){0.f, 0.f, 0.f, 0.f}; rs[t] = 0.f; }

    const float4v zero = (float4v){0.f, 0.f, 0.f, 0.f};

    const int q0beg = qh * 512;
    for (int q0 = q0beg; q0 < q0beg + 512; q0 += 16) {
        const half4v kf = *(const half4v*)(Kh + (size_t)(q0 + l16) * 16 + lg * 4);
        const half4v vf = *(const half4v*)(Vh + (size_t)((q0 >> 4) * 16 + l16) * 16 + lg * 4);
#pragma unroll
        for (int t = 0; t < 4; ++t) {
            float4v s = __builtin_amdgcn_mfma_f32_16x16x16f16(kf, qf[t], zero, 0, 0, 0);
            const float e0 = __builtin_amdgcn_exp2f(s[0]);
            const float e1 = __builtin_amdgcn_exp2f(s[1]);
            const float e2 = __builtin_amdgcn_exp2f(s[2]);
            const float e3 = __builtin_amdgcn_exp2f(s[3]);
            rs[t] += (e0 + e1) + (e2 + e3);
            half4v pf;
            pf[0] = (_Float16)e0; pf[1] = (_Float16)e1;
            pf[2] = (_Float16)e2; pf[3] = (_Float16)e3;
            o[t] = __builtin_amdgcn_mfma_f32_16x16x16f16(vf, pf, o[t], 0, 0, 0);
        }
    }

    __shared__ float Ored[2][64][16];
    __shared__ float Rred[2][64][4];
    if (qh == 1) {
#pragma unroll
        for (int t = 0; t < 4; ++t) {
#pragma unroll
            for (int rr = 0; rr < 4; ++rr) Ored[pg][lane][t * 4 + rr] = o[t][rr];
            Rred[pg][lane][t] = rs[t];
        }
    }
    __syncthreads();
    if (qh == 0) {
#pragma unroll
        for (int t = 0; t < 4; ++t) {
#pragma unroll
            for (int rr = 0; rr < 4; ++rr) o[t][rr] += Ored[pg][lane][t * 4 + rr];
            rs[t] += Rred[pg][lane][t];
        }
#pragma unroll
        for (int t = 0; t < 4; ++t) {
            float r = rs[t];
            r += __shfl_xor(r, 16);
            r += __shfl_xor(r, 32);
            const float inv = 1.0f / r;
            half4v h;
#pragma unroll
            for (int rr = 0; rr < 4; ++rr) h[rr] = (_Float16)(o[t][rr] * inv);
            // K32 layout: [b][pgrp][n>>1][p16][ (n&1)*16 + lg*4 ]
            *(half4v*)(aF + (((size_t)(b * 64 + (pbase >> 4) + t) * 4 + (n >> 1)) * 16 + l16) * 32
                          + (n & 1) * 16 + lg * 4) = h;
        }
    }
}

// ---------------- K3: attn projection MFMA GEMM (K32, no LDS) ----------------
__global__ __launch_bounds__(256) void proj_kernel(
    const _Float16* __restrict__ aF, const _Float16* __restrict__ wP,
    const float* __restrict__ attn_b, float* __restrict__ out)
{
    const int pt = blockIdx.x;   // 0..15 (64 pixels)
    const int ot = blockIdx.y;   // 0..1  (64 outputs)
    const int b  = blockIdx.z;
    const int lane = threadIdx.x & 63, w = threadIdx.x >> 6;
    const int l16 = lane & 15, hi = lane >> 4;
    const int p0 = pt * 64;
    const int o0 = ot * 64 + w * 16;

    float4v acc[4];
#pragma unroll
    for (int pg = 0; pg < 4; ++pg) acc[pg] = (float4v){0.f, 0.f, 0.f, 0.f};

    for (int kc = 0; kc < 4; ++kc) {
        const half8v a = *(const half8v*)(wP + ((size_t)kc * DV_ + o0 + l16) * 32 + hi * 8);
#pragma unroll
        for (int pg = 0; pg < 4; ++pg) {
            const half8v bf = *(const half8v*)(aF + (((size_t)(b * 64 + pt * 4 + pg) * 4 + kc) * 16 + l16) * 32 + hi * 8);
            acc[pg] = __builtin_amdgcn_mfma_f32_16x16x32_f16(a, bf, acc[pg], 0, 0, 0);
        }
    }
#pragma unroll
    for (int pg = 0; pg < 4; ++pg) {
        const int p = p0 + pg * 16 + l16;
#pragma unroll
        for (int r = 0; r < 4; ++r) {
            const int o = o0 + hi * 4 + r;
            out[((size_t)(b * COUT_ + CCONV_ + o)) * HW_ + p] = acc[pg][r] + attn_b[o];
        }
    }
}

// ---------------- K4: 3x3 conv — branch-free implicit GEMM over shifted copies ----------------
// Wave: 1 row x 32 px x 32 co (2 co-chunks); block = 4 waves = all 128 co of one row.
// Per (kc,kh,kw): 2 A-loads + 2 B-loads (contiguous 1KB) -> 4 MFMA. Zero branches.
__global__ __launch_bounds__(256) void conv_kernel(
    const _Float16* __restrict__ xFs, const _Float16* __restrict__ wC,
    const float* __restrict__ conv_b, float* __restrict__ out)
{
    const int r = blockIdx.x;      // output row 0..31
    const int b = blockIdx.y;
    const int t = threadIdx.x;
    const int lane = t & 63, w = t >> 6;
    const int l16 = lane & 15, hi = lane >> 4;

    float4v acc[2][2];
#pragma unroll
    for (int i = 0; i < 2; ++i)
#pragma unroll
        for (int j = 0; j < 2; ++j) acc[i][j] = (float4v){0.f, 0.f, 0.f, 0.f};

#pragma unroll
    for (int kc = 0; kc < 8; ++kc) {
        const size_t xrow = (((size_t)b * 8 + kc) * 34 + r) * 1024 + l16 * 32 + hi * 8;
        const _Float16* ab = wC + ((size_t)(kc * 9) * 8 + 2 * w) * 512 + l16 * 32 + hi * 8;
#pragma unroll
        for (int kh = 0; kh < 3; ++kh) {
#pragma unroll
            for (int kw = 0; kw < 3; ++kw) {
                const int cp = (kw == 0) ? 1 : ((kw == 1) ? 0 : 2);   // minus/center/plus
                const _Float16* a = ab + (size_t)((kh * 3 + kw) * 8) * 512;
                const half8v a0 = *(const half8v*)(a);
                const half8v a1 = *(const half8v*)(a + 512);
                const _Float16* xp = xFs + (size_t)cp * XFS_SZ + xrow + (size_t)kh * 1024;
                const half8v b0 = *(const half8v*)(xp);
                const half8v b1 = *(const half8v*)(xp + 16 * 32);
                acc[0][0] = __builtin_amdgcn_mfma_f32_16x16x32_f16(a0, b0, acc[0][0], 0, 0, 0);
                acc[0][1] = __builtin_amdgcn_mfma_f32_16x16x32_f16(a0, b1, acc[0][1], 0, 0, 0);
                acc[1][0] = __builtin_amdgcn_mfma_f32_16x16x32_f16(a1, b0, acc[1][0], 0, 0, 0);
                acc[1][1] = __builtin_amdgcn_mfma_f32_16x16x32_f16(a1, b1, acc[1][1], 0, 0, 0);
            }
        }
    }
#pragma unroll
    for (int cg = 0; cg < 2; ++cg)
#pragma unroll
        for (int rr = 0; rr < 4; ++rr) {
            const int co = (2 * w + cg) * 16 + hi * 4 + rr;
            const float bias = conv_b[co];
            float* dst = out + (size_t)(b * COUT_ + co) * HW_ + r * 32;
            dst[l16]      = acc[cg][0][rr] + bias;
            dst[16 + l16] = acc[cg][1][rr] + bias;
        }
}

extern "C" void kernel_launch(void* const* d_in, const int* in_sizes, int n_in,
                              void* d_out, int out_size, void* d_ws, size_t ws_size,
                              hipStream_t stream)
{
    (void)in_sizes; (void)n_in; (void)out_size; (void)ws_size;
    const float* x      = (const float*)d_in[0];
    const float* conv_w = (const float*)d_in[1];
    const float* conv_b = (const float*)d_in[2];
    const float* qkv_w  = (const float*)d_in[3];
    const float* qkv_b  = (const float*)d_in[4];
    const float* attn_w = (const float*)d_in[5];
    const float* attn_b = (const float*)d_in[6];
    float* out = (float*)d_out;

    char* ws = (char*)d_ws;
    _Float16* xFs = (_Float16*)(ws);                // 3 x 8,912,896 = 26,738,688
    _Float16* wC  = (_Float16*)(ws + 26738688);     //   589,824
    _Float16* wF  = (_Float16*)(ws + 27328512);     //   196,608
    _Float16* wP  = (_Float16*)(ws + 27525120);     //    32,768
    _Float16* Qt  = (_Float16*)(ws + 27557888);     // 4,194,304
    _Float16* Kt  = (_Float16*)(ws + 31752192);     // 4,194,304
    _Float16* vF  = (_Float16*)(ws + 35946496);     // 4,194,304
    _Float16* aF  = (_Float16*)(ws + 40140800);     // 4,194,304 (end 44,335,104)

    xt_kernel<<<dim3(32, 8, B_), dim3(256), 0, stream>>>(x, xFs);
    wprep_kernel<<<dim3(240), dim3(256), 0, stream>>>(conv_w, qkv_w, attn_w, wC, wF, wP);
    qkv_kernel<<<dim3(16, 6, B_), dim3(256), 0, stream>>>(xFs, wF, qkv_b, Qt, Kt, vF);
    attn_kernel<<<dim3(1024), dim3(256), 0, stream>>>(Qt, Kt, vF, aF);
    proj_kernel<<<dim3(16, 2, B_), dim3(256), 0, stream>>>(aF, wP, attn_b, out);
    conv_kernel<<<dim3(32, B_), dim3(256), 0, stream>>>(xFs, wC, conv_b, out);
}